// Round 1
// baseline (1243.257 us; speedup 1.0000x reference)
//
#include <hip/hip_runtime.h>

// Paired CGCNN (separated) — fp32 implementation.
// Structure per branch: embed -> 3x fused conv (y1/y2 precompute + gather) -> pool -> dense.
// Then |A-B| -> FF(softplus) -> linear head.

constexpr int NATOM = 20000;
constexpr int MNBR  = 12;
constexpr int ORIG  = 92;
constexpr int NBRF  = 41;
constexpr int F     = 64;
constexpr int H     = 128;
constexpr int NCONV = 3;
constexpr int NCRYS = 400;

#define DEVFN __device__ __forceinline__

DEVFN float softplusf(float x) {
    // stable: max(x,0) + log1p(exp(-|x|))
    return fmaxf(x, 0.f) + __logf(1.f + __expf(-fabsf(x)));
}
DEVFN float sigmoidf(float x) {
    return __builtin_amdgcn_rcpf(1.f + __expf(-x));
}

template <typename T>
DEVFN const T* upt(const T* p) {
    // force pointer into SGPRs so subsequent uniform loads become s_load
    unsigned long long v = (unsigned long long)p;
    unsigned lo = __builtin_amdgcn_readfirstlane((unsigned)v);
    unsigned hi = __builtin_amdgcn_readfirstlane((unsigned)(v >> 32));
    return (const T*)((((unsigned long long)hi) << 32) | lo);
}

// ---------------- embed: a = atom_fea @ emb_W + emb_b  (N,92)@(92,64) ----------------
__global__ __launch_bounds__(256) void k_embed(const float* __restrict__ atom,
                                               const float* __restrict__ W,
                                               const float* __restrict__ b,
                                               float* __restrict__ out) {
    __shared__ float sW[ORIG * F];
    for (int i = threadIdx.x; i < ORIG * F; i += 256) sW[i] = W[i];
    __syncthreads();
    int n = blockIdx.x * 4 + (threadIdx.x >> 6);
    int f = threadIdx.x & 63;
    const float* ar = upt(atom + n * ORIG);  // wave-uniform row -> s_loads
    float acc = b[f];
#pragma unroll
    for (int k = 0; k < ORIG; ++k) acc += ar[k] * sW[k * F + f];
    out[n * F + f] = acc;
}

// ---------------- y12: y1 = a@W[0:64,:], y2 = a@W[64:128,:]  per conv layer ----------------
__global__ __launch_bounds__(256) void k_y12(const float* __restrict__ a,
                                             const float* __restrict__ W,  // (169,128), rows 0..127 used
                                             float* __restrict__ y1,
                                             float* __restrict__ y2) {
    __shared__ __align__(16) float sAT[F][16];  // transposed a-tile: 16 atoms
    int base = blockIdx.x * 16;
    int t = threadIdx.x;
#pragma unroll
    for (int i = 0; i < 4; ++i) {
        int e = t + i * 256;
        sAT[e & 63][e >> 6] = a[base * F + e];
    }
    __syncthreads();
    int c = t;  // 0..255 : c<128 -> y1 col c ; else y2 col c-128
    const float* wp = (c < 128) ? (W + c) : (W + 64 * H + (c - 128));
    float acc[16];
#pragma unroll
    for (int r = 0; r < 16; ++r) acc[r] = 0.f;
#pragma unroll
    for (int k = 0; k < F; ++k) {
        float w = wp[k * H];
        const float4* rp = reinterpret_cast<const float4*>(&sAT[k][0]);
        float4 v0 = rp[0], v1 = rp[1], v2 = rp[2], v3 = rp[3];
        acc[0] += v0.x * w;  acc[1] += v0.y * w;  acc[2] += v0.z * w;  acc[3] += v0.w * w;
        acc[4] += v1.x * w;  acc[5] += v1.y * w;  acc[6] += v1.z * w;  acc[7] += v1.w * w;
        acc[8] += v2.x * w;  acc[9] += v2.y * w;  acc[10] += v2.z * w; acc[11] += v2.w * w;
        acc[12] += v3.x * w; acc[13] += v3.y * w; acc[14] += v3.z * w; acc[15] += v3.w * w;
    }
    float* dst = (c < 128) ? (y1 + base * H + c) : (y2 + base * H + (c - 128));
#pragma unroll
    for (int r = 0; r < 16; ++r) dst[r * H] = acc[r];
}

// ---------------- fused conv layer (in-place update of a) ----------------
__global__ __launch_bounds__(256) void k_conv(const float* __restrict__ y1,
                                              const float* __restrict__ y2,
                                              const float* __restrict__ nbr,   // (N,12,41)
                                              const int* __restrict__ idx,     // (N,12)
                                              const float* __restrict__ W3,    // (41,128)
                                              const float* __restrict__ bias,  // (128)
                                              const float* __restrict__ bn1,   // (4,128)
                                              const float* __restrict__ bn2,   // (4,64)
                                              float* __restrict__ a) {
    __shared__ float sS1[128], sH1[128], sS2[64], sH2[64];
    int t = threadIdx.x;
    if (t < 128) {
        float g = bn1[t], be = bn1[128 + t], mu = bn1[256 + t], va = bn1[384 + t];
        float s = g * rsqrtf(va + 1e-5f);
        sS1[t] = s;
        sH1[t] = be - mu * s + bias[t] * s;  // fold conv bias into bn shift
    } else if (t < 192) {
        int u = t - 128;
        float g = bn2[u], be = bn2[64 + u], mu = bn2[128 + u], va = bn2[192 + u];
        float s = g * rsqrtf(va + 1e-5f);
        sS2[u] = s;
        sH2[u] = be - mu * s;
    }
    __syncthreads();

    int i = blockIdx.x * 4 + (t >> 6);  // one wave per atom
    int f = t & 63;

    // W3 columns f and f+64 into registers (reused across all 12 neighbors)
    float w3a[NBRF], w3b[NBRF];
#pragma unroll
    for (int k = 0; k < NBRF; ++k) {
        w3a[k] = W3[k * H + f];
        w3b[k] = W3[k * H + 64 + f];
    }

    const int* ip = upt(idx + i * MNBR);  // uniform -> s_load
    int js[MNBR];
#pragma unroll
    for (int m = 0; m < MNBR; ++m) js[m] = ip[m];

    // prefetch all gathered y2 values (latency hiding)
    float pf[MNBR], pc[MNBR];
#pragma unroll
    for (int m = 0; m < MNBR; ++m) {
        pf[m] = y2[js[m] * H + f];
        pc[m] = y2[js[m] * H + 64 + f];
    }

    float yf = y1[i * H + f], yc = y1[i * H + 64 + f];
    const float* nbu = upt(nbr + (size_t)i * MNBR * NBRF);  // uniform row -> s_loads

    float s1f = sS1[f], h1f = sH1[f], s1c = sS1[64 + f], h1c = sH1[64 + f];
    float s2 = sS2[f], h2 = sH2[f];

    float sacc = 0.f;
#pragma unroll
    for (int m = 0; m < MNBR; ++m) {
        float zf = yf + pf[m];
        float zc = yc + pc[m];
        const float* nb = nbu + m * NBRF;
#pragma unroll
        for (int k = 0; k < NBRF; ++k) {
            float nv = nb[k];  // scalar (wave-uniform) operand
            zf += nv * w3a[k];
            zc += nv * w3b[k];
        }
        zf = zf * s1f + h1f;
        zc = zc * s1c + h1c;
        sacc += sigmoidf(zf) * softplusf(zc);
    }
    float av = a[i * F + f];
    a[i * F + f] = softplusf(av + sacc * s2 + h2);
}

// ---------------- pool: atomic segment sum + count ----------------
__global__ __launch_bounds__(256) void k_pool(const float* __restrict__ a,
                                              const int* __restrict__ seg,
                                              float* __restrict__ pool,
                                              float* __restrict__ cnt) {
    int idx = blockIdx.x * 256 + threadIdx.x;  // over N*F (exact multiple)
    int n = idx >> 6, f = idx & 63;
    int c = seg[n];
    atomicAdd(&pool[c * F + f], a[idx]);
    if (f == 0) atomicAdd(&cnt[c], 1.f);
}

// ---------------- dense: crys = softplus(mean @ dense_W + b)  (400,64)@(64,128) ----------------
__global__ __launch_bounds__(128) void k_dense(const float* __restrict__ pool,
                                               const float* __restrict__ cnt,
                                               const float* __restrict__ W,  // (64,128)
                                               const float* __restrict__ b,
                                               float* __restrict__ crys) {
    int c = blockIdx.x;
    int h = threadIdx.x;
    __shared__ float sp[F];
    if (h < F) sp[h] = pool[c * F + h] / fmaxf(cnt[c], 1.f);
    __syncthreads();
    float acc = b[h];
#pragma unroll
    for (int k = 0; k < F; ++k) acc += sp[k] * W[k * H + h];
    crys[c * H + h] = softplusf(acc);
}

// ---------------- combine: |A-B| -> softplus(ff) -> head ----------------
__global__ __launch_bounds__(128) void k_combine(const float* __restrict__ cA,
                                                 const float* __restrict__ cB,
                                                 const float* __restrict__ ffW,   // (128,128)
                                                 const float* __restrict__ ffb,   // (128)
                                                 const float* __restrict__ outW,  // (128)
                                                 const float* __restrict__ outb,  // (1)
                                                 float* __restrict__ out) {
    int c = blockIdx.x;
    int h = threadIdx.x;
    __shared__ float sd[H];
    __shared__ float st[H];
    sd[h] = fabsf(cA[c * H + h] - cB[c * H + h]);
    __syncthreads();
    float acc = ffb[h];
#pragma unroll
    for (int k = 0; k < H; ++k) acc += sd[k] * ffW[k * H + h];
    st[h] = softplusf(acc) * outW[h];
    __syncthreads();
    for (int s = 64; s > 0; s >>= 1) {
        if (h < s) st[h] += st[h + s];
        __syncthreads();
    }
    if (h == 0) out[c] = st[0] + outb[0];
}

extern "C" void kernel_launch(void* const* d_in, const int* in_sizes, int n_in,
                              void* d_out, int out_size, void* d_ws, size_t ws_size,
                              hipStream_t stream) {
    // input order = setup_inputs() dict order
    // per-branch block of 12: [atom_fea, nbr_fea, nbr_fea_idx, crystal_atom_idx,
    //                          emb_W, emb_b, conv_W, conv_b, conv_bn1, conv_bn2, dense_W, dense_b]
    const float* ffW  = (const float*)d_in[24];  // (1,128,128)
    const float* ffb  = (const float*)d_in[25];
    const float* outW = (const float*)d_in[26];
    const float* outb = (const float*)d_in[27];

    float* ws = (float*)d_ws;
    float* aA    = ws;                      // N*F
    float* aB    = aA + NATOM * F;          // N*F
    float* y1    = aB + NATOM * F;          // N*H
    float* y2    = y1 + NATOM * H;          // N*H
    float* poolA = y2 + NATOM * H;          // NCRYS*F
    float* poolB = poolA + NCRYS * F;       // NCRYS*F
    float* cntA  = poolB + NCRYS * F;       // NCRYS
    float* cntB  = cntA + NCRYS;            // NCRYS
    float* crA   = cntB + NCRYS;            // NCRYS*H
    float* crB   = crA + NCRYS * H;         // NCRYS*H

    // zero pool sums + counts (ws is NOT re-poisoned between replays)
    hipMemsetAsync(poolA, 0, (size_t)(2 * NCRYS * F + 2 * NCRYS) * sizeof(float), stream);

    for (int br = 0; br < 2; ++br) {
        int o = br * 12;
        const float* atom  = (const float*)d_in[o + 0];
        const float* nbrf  = (const float*)d_in[o + 1];
        const int*   nidx  = (const int*)d_in[o + 2];
        const int*   seg   = (const int*)d_in[o + 3];
        const float* embW  = (const float*)d_in[o + 4];
        const float* embb  = (const float*)d_in[o + 5];
        const float* convW = (const float*)d_in[o + 6];
        const float* convb = (const float*)d_in[o + 7];
        const float* bn1   = (const float*)d_in[o + 8];
        const float* bn2   = (const float*)d_in[o + 9];
        const float* denW  = (const float*)d_in[o + 10];
        const float* denb  = (const float*)d_in[o + 11];

        float* a    = br ? aB : aA;
        float* pool = br ? poolB : poolA;
        float* cnt  = br ? cntB : cntA;
        float* cr   = br ? crB : crA;

        k_embed<<<NATOM / 4, 256, 0, stream>>>(atom, embW, embb, a);
        for (int l = 0; l < NCONV; ++l) {
            const float* Wl = convW + (size_t)l * (2 * F + NBRF) * H;  // (169,128)
            k_y12<<<NATOM / 16, 256, 0, stream>>>(a, Wl, y1, y2);
            k_conv<<<NATOM / 4, 256, 0, stream>>>(y1, y2, nbrf, nidx,
                                                  Wl + 128 * H,          // W3 (41,128)
                                                  convb + l * H,
                                                  bn1 + l * 4 * H,
                                                  bn2 + l * 4 * F,
                                                  a);
        }
        k_pool<<<NATOM * F / 256, 256, 0, stream>>>(a, seg, pool, cnt);
        k_dense<<<NCRYS, 128, 0, stream>>>(pool, cnt, denW, denb, cr);
    }

    k_combine<<<NCRYS, 128, 0, stream>>>(crA, crB, ffW, ffb, outW, outb, (float*)d_out);
}

// Round 2
// 602.323 us; speedup vs baseline: 2.0641x; 2.0641x over previous
//
#include <hip/hip_runtime.h>

// Paired CGCNN (separated) — fp32 implementation, R1.
// R1 change: k_conv no longer streams nbr_fea via scalar loads; it stages the
// block's nbr rows into LDS (coalesced vector loads, 44-float padded rows) and
// broadcasts via ds_read_b128. W3 columns forced into VGPRs (float4 arrays,
// static indexing, __launch_bounds__(256,2)).

constexpr int NATOM = 20000;
constexpr int MNBR  = 12;
constexpr int ORIG  = 92;
constexpr int NBRF  = 41;
constexpr int F     = 64;
constexpr int H     = 128;
constexpr int NCONV = 3;
constexpr int NCRYS = 400;

constexpr int NVPAD = 44;              // padded neighbor row (16B-aligned float4 reads)
constexpr int ATOMROW = MNBR * NVPAD;  // 528 floats per atom in LDS

#define DEVFN __device__ __forceinline__

DEVFN float softplusf(float x) {
    return fmaxf(x, 0.f) + __logf(1.f + __expf(-fabsf(x)));
}
DEVFN float sigmoidf(float x) {
    return __builtin_amdgcn_rcpf(1.f + __expf(-x));
}

template <typename T>
DEVFN const T* upt(const T* p) {
    unsigned long long v = (unsigned long long)p;
    unsigned lo = __builtin_amdgcn_readfirstlane((unsigned)v);
    unsigned hi = __builtin_amdgcn_readfirstlane((unsigned)(v >> 32));
    return (const T*)((((unsigned long long)hi) << 32) | lo);
}

// ---------------- embed: a = atom_fea @ emb_W + emb_b  (N,92)@(92,64) ----------------
__global__ __launch_bounds__(256) void k_embed(const float* __restrict__ atom,
                                               const float* __restrict__ W,
                                               const float* __restrict__ b,
                                               float* __restrict__ out) {
    __shared__ float sW[ORIG * F];
    for (int i = threadIdx.x; i < ORIG * F; i += 256) sW[i] = W[i];
    __syncthreads();
    int n = blockIdx.x * 4 + (threadIdx.x >> 6);
    int f = threadIdx.x & 63;
    const float* ar = upt(atom + n * ORIG);
    float acc = b[f];
#pragma unroll
    for (int k = 0; k < ORIG; ++k) acc += ar[k] * sW[k * F + f];
    out[n * F + f] = acc;
}

// ---------------- y12: y1 = a@W[0:64,:], y2 = a@W[64:128,:] ----------------
__global__ __launch_bounds__(256) void k_y12(const float* __restrict__ a,
                                             const float* __restrict__ W,  // (169,128)
                                             float* __restrict__ y1,
                                             float* __restrict__ y2) {
    __shared__ __align__(16) float sAT[F][16];
    int base = blockIdx.x * 16;
    int t = threadIdx.x;
#pragma unroll
    for (int i = 0; i < 4; ++i) {
        int e = t + i * 256;
        sAT[e & 63][e >> 6] = a[base * F + e];
    }
    __syncthreads();
    int c = t;
    const float* wp = (c < 128) ? (W + c) : (W + 64 * H + (c - 128));
    float acc[16];
#pragma unroll
    for (int r = 0; r < 16; ++r) acc[r] = 0.f;
#pragma unroll
    for (int k = 0; k < F; ++k) {
        float w = wp[k * H];
        const float4* rp = reinterpret_cast<const float4*>(&sAT[k][0]);
        float4 v0 = rp[0], v1 = rp[1], v2 = rp[2], v3 = rp[3];
        acc[0] += v0.x * w;  acc[1] += v0.y * w;  acc[2] += v0.z * w;  acc[3] += v0.w * w;
        acc[4] += v1.x * w;  acc[5] += v1.y * w;  acc[6] += v1.z * w;  acc[7] += v1.w * w;
        acc[8] += v2.x * w;  acc[9] += v2.y * w;  acc[10] += v2.z * w; acc[11] += v2.w * w;
        acc[12] += v3.x * w; acc[13] += v3.y * w; acc[14] += v3.z * w; acc[15] += v3.w * w;
    }
    float* dst = (c < 128) ? (y1 + base * H + c) : (y2 + base * H + (c - 128));
#pragma unroll
    for (int r = 0; r < 16; ++r) dst[r * H] = acc[r];
}

// ---------------- fused conv layer (in-place update of a) ----------------
__global__ __launch_bounds__(256, 2) void k_conv(const float* __restrict__ y1,
                                                 const float* __restrict__ y2,
                                                 const float* __restrict__ nbr,   // (N,12,41)
                                                 const int* __restrict__ idx,     // (N,12)
                                                 const float* __restrict__ W3,    // (41,128)
                                                 const float* __restrict__ bias,  // (128)
                                                 const float* __restrict__ bn1,   // (4,128)
                                                 const float* __restrict__ bn2,   // (4,64)
                                                 float* __restrict__ a) {
    __shared__ __align__(16) float snv[4 * ATOMROW];  // 4 atoms x 12 nbr x 44 floats
    __shared__ float sS1[128], sH1[128], sS2[64], sH2[64];
    int t = threadIdx.x;
    if (t < 128) {
        float g = bn1[t], be = bn1[128 + t], mu = bn1[256 + t], va = bn1[384 + t];
        float s = g * rsqrtf(va + 1e-5f);
        sS1[t] = s;
        sH1[t] = be - mu * s + bias[t] * s;
    } else if (t < 192) {
        int u = t - 128;
        float g = bn2[u], be = bn2[64 + u], mu = bn2[128 + u], va = bn2[192 + u];
        float s = g * rsqrtf(va + 1e-5f);
        sS2[u] = s;
        sH2[u] = be - mu * s;
    }

    // stage 4 contiguous atoms' nbr rows: coalesced vector-path loads -> padded LDS
    {
        const float* g = nbr + (size_t)blockIdx.x * (4 * MNBR * NBRF);
#pragma unroll
        for (int it = 0; it < 8; ++it) {
            int e = t + it * 256;
            if (e < 4 * MNBR * NBRF) {
                int a_ = e / (MNBR * NBRF);
                int r  = e - a_ * (MNBR * NBRF);
                int m  = r / NBRF;
                int k  = r - m * NBRF;
                snv[a_ * ATOMROW + m * NVPAD + k] = g[e];
            }
        }
    }
    __syncthreads();

    int w = t >> 6;
    int f = t & 63;
    int i = blockIdx.x * 4 + w;

    // W3 columns f and f+64 in explicit float4 registers (static indexing only)
    float4 wA[10], wB[10];
#pragma unroll
    for (int c = 0; c < 10; ++c) {
        wA[c] = make_float4(W3[(4 * c + 0) * H + f], W3[(4 * c + 1) * H + f],
                            W3[(4 * c + 2) * H + f], W3[(4 * c + 3) * H + f]);
        wB[c] = make_float4(W3[(4 * c + 0) * H + 64 + f], W3[(4 * c + 1) * H + 64 + f],
                            W3[(4 * c + 2) * H + 64 + f], W3[(4 * c + 3) * H + 64 + f]);
    }
    float wA40 = W3[40 * H + f];
    float wB40 = W3[40 * H + 64 + f];

    const int* ip = upt(idx + i * MNBR);
    int js[MNBR];
#pragma unroll
    for (int m = 0; m < MNBR; ++m) js[m] = ip[m];

    float pf[MNBR], pc[MNBR];
#pragma unroll
    for (int m = 0; m < MNBR; ++m) {
        pf[m] = y2[js[m] * H + f];
        pc[m] = y2[js[m] * H + 64 + f];
    }

    float yf = y1[i * H + f], yc = y1[i * H + 64 + f];
    float s1f = sS1[f], h1f = sH1[f], s1c = sS1[64 + f], h1c = sH1[64 + f];
    float s2 = sS2[f], h2 = sH2[f];

    const float* base = &snv[w * ATOMROW];  // wave-uniform -> ds broadcast reads
    float sacc = 0.f;
#pragma unroll
    for (int m = 0; m < MNBR; ++m) {
        const float4* nv4 = reinterpret_cast<const float4*>(base + m * NVPAD);
        float zf0 = yf + pf[m], zc0 = yc + pc[m];
        float zf1 = 0.f, zc1 = 0.f;
#pragma unroll
        for (int c = 0; c < 10; ++c) {
            float4 q = nv4[c];
            zf0 = fmaf(q.x, wA[c].x, zf0);
            zc0 = fmaf(q.x, wB[c].x, zc0);
            zf1 = fmaf(q.y, wA[c].y, zf1);
            zc1 = fmaf(q.y, wB[c].y, zc1);
            zf0 = fmaf(q.z, wA[c].z, zf0);
            zc0 = fmaf(q.z, wB[c].z, zc0);
            zf1 = fmaf(q.w, wA[c].w, zf1);
            zc1 = fmaf(q.w, wB[c].w, zc1);
        }
        float nv40 = base[m * NVPAD + 40];
        float zf = fmaf(nv40, wA40, zf0 + zf1);
        float zc = fmaf(nv40, wB40, zc0 + zc1);
        zf = zf * s1f + h1f;
        zc = zc * s1c + h1c;
        sacc += sigmoidf(zf) * softplusf(zc);
    }
    float av = a[i * F + f];
    a[i * F + f] = softplusf(av + sacc * s2 + h2);
}

// ---------------- pool: atomic segment sum + count ----------------
__global__ __launch_bounds__(256) void k_pool(const float* __restrict__ a,
                                              const int* __restrict__ seg,
                                              float* __restrict__ pool,
                                              float* __restrict__ cnt) {
    int idx = blockIdx.x * 256 + threadIdx.x;
    int n = idx >> 6, f = idx & 63;
    int c = seg[n];
    atomicAdd(&pool[c * F + f], a[idx]);
    if (f == 0) atomicAdd(&cnt[c], 1.f);
}

// ---------------- dense ----------------
__global__ __launch_bounds__(128) void k_dense(const float* __restrict__ pool,
                                               const float* __restrict__ cnt,
                                               const float* __restrict__ W,
                                               const float* __restrict__ b,
                                               float* __restrict__ crys) {
    int c = blockIdx.x;
    int h = threadIdx.x;
    __shared__ float sp[F];
    if (h < F) sp[h] = pool[c * F + h] / fmaxf(cnt[c], 1.f);
    __syncthreads();
    float acc = b[h];
#pragma unroll
    for (int k = 0; k < F; ++k) acc += sp[k] * W[k * H + h];
    crys[c * H + h] = softplusf(acc);
}

// ---------------- combine ----------------
__global__ __launch_bounds__(128) void k_combine(const float* __restrict__ cA,
                                                 const float* __restrict__ cB,
                                                 const float* __restrict__ ffW,
                                                 const float* __restrict__ ffb,
                                                 const float* __restrict__ outW,
                                                 const float* __restrict__ outb,
                                                 float* __restrict__ out) {
    int c = blockIdx.x;
    int h = threadIdx.x;
    __shared__ float sd[H];
    __shared__ float st[H];
    sd[h] = fabsf(cA[c * H + h] - cB[c * H + h]);
    __syncthreads();
    float acc = ffb[h];
#pragma unroll
    for (int k = 0; k < H; ++k) acc += sd[k] * ffW[k * H + h];
    st[h] = softplusf(acc) * outW[h];
    __syncthreads();
    for (int s = 64; s > 0; s >>= 1) {
        if (h < s) st[h] += st[h + s];
        __syncthreads();
    }
    if (h == 0) out[c] = st[0] + outb[0];
}

extern "C" void kernel_launch(void* const* d_in, const int* in_sizes, int n_in,
                              void* d_out, int out_size, void* d_ws, size_t ws_size,
                              hipStream_t stream) {
    const float* ffW  = (const float*)d_in[24];
    const float* ffb  = (const float*)d_in[25];
    const float* outW = (const float*)d_in[26];
    const float* outb = (const float*)d_in[27];

    float* ws = (float*)d_ws;
    float* aA    = ws;
    float* aB    = aA + NATOM * F;
    float* y1    = aB + NATOM * F;
    float* y2    = y1 + NATOM * H;
    float* poolA = y2 + NATOM * H;
    float* poolB = poolA + NCRYS * F;
    float* cntA  = poolB + NCRYS * F;
    float* cntB  = cntA + NCRYS;
    float* crA   = cntB + NCRYS;
    float* crB   = crA + NCRYS * H;

    hipMemsetAsync(poolA, 0, (size_t)(2 * NCRYS * F + 2 * NCRYS) * sizeof(float), stream);

    for (int br = 0; br < 2; ++br) {
        int o = br * 12;
        const float* atom  = (const float*)d_in[o + 0];
        const float* nbrf  = (const float*)d_in[o + 1];
        const int*   nidx  = (const int*)d_in[o + 2];
        const int*   seg   = (const int*)d_in[o + 3];
        const float* embW  = (const float*)d_in[o + 4];
        const float* embb  = (const float*)d_in[o + 5];
        const float* convW = (const float*)d_in[o + 6];
        const float* convb = (const float*)d_in[o + 7];
        const float* bn1   = (const float*)d_in[o + 8];
        const float* bn2   = (const float*)d_in[o + 9];
        const float* denW  = (const float*)d_in[o + 10];
        const float* denb  = (const float*)d_in[o + 11];

        float* a    = br ? aB : aA;
        float* pool = br ? poolB : poolA;
        float* cnt  = br ? cntB : cntA;
        float* cr   = br ? crB : crA;

        k_embed<<<NATOM / 4, 256, 0, stream>>>(atom, embW, embb, a);
        for (int l = 0; l < NCONV; ++l) {
            const float* Wl = convW + (size_t)l * (2 * F + NBRF) * H;
            k_y12<<<NATOM / 16, 256, 0, stream>>>(a, Wl, y1, y2);
            k_conv<<<NATOM / 4, 256, 0, stream>>>(y1, y2, nbrf, nidx,
                                                  Wl + 128 * H,
                                                  convb + l * H,
                                                  bn1 + l * 4 * H,
                                                  bn2 + l * 4 * F,
                                                  a);
        }
        k_pool<<<NATOM * F / 256, 256, 0, stream>>>(a, seg, pool, cnt);
        k_dense<<<NCRYS, 128, 0, stream>>>(pool, cnt, denW, denb, cr);
    }

    k_combine<<<NCRYS, 128, 0, stream>>>(crA, crB, ffW, ffb, outW, outb, (float*)d_out);
}

// Round 3
// 582.564 us; speedup vs baseline: 2.1341x; 1.0339x over previous
//
#include <hip/hip_runtime.h>

// Paired CGCNN (separated) — fp32, R2.
// R2 change (k_conv only): k-quad-outer / neighbor-inner loop so W3 weights are
// STREAMED (8 L1-hit loads per quad, 1-deep prefetch) instead of expecting 80
// resident VGPRs the allocator refuses to give. Persistent accumulators
// zf[12]/zc[12]; nv quads via ds_read_b128 broadcast. launch_bounds(256,4).

constexpr int NATOM = 20000;
constexpr int MNBR  = 12;
constexpr int ORIG  = 92;
constexpr int NBRF  = 41;
constexpr int F     = 64;
constexpr int H     = 128;
constexpr int NCONV = 3;
constexpr int NCRYS = 400;

constexpr int NVPAD = 44;              // padded neighbor row (16B-aligned float4 reads)
constexpr int ATOMROW = MNBR * NVPAD;  // 528 floats per atom in LDS

#define DEVFN __device__ __forceinline__

DEVFN float softplusf(float x) {
    return fmaxf(x, 0.f) + __logf(1.f + __expf(-fabsf(x)));
}
DEVFN float sigmoidf(float x) {
    return __builtin_amdgcn_rcpf(1.f + __expf(-x));
}

template <typename T>
DEVFN const T* upt(const T* p) {
    unsigned long long v = (unsigned long long)p;
    unsigned lo = __builtin_amdgcn_readfirstlane((unsigned)v);
    unsigned hi = __builtin_amdgcn_readfirstlane((unsigned)(v >> 32));
    return (const T*)((((unsigned long long)hi) << 32) | lo);
}

// ---------------- embed ----------------
__global__ __launch_bounds__(256) void k_embed(const float* __restrict__ atom,
                                               const float* __restrict__ W,
                                               const float* __restrict__ b,
                                               float* __restrict__ out) {
    __shared__ float sW[ORIG * F];
    for (int i = threadIdx.x; i < ORIG * F; i += 256) sW[i] = W[i];
    __syncthreads();
    int n = blockIdx.x * 4 + (threadIdx.x >> 6);
    int f = threadIdx.x & 63;
    const float* ar = upt(atom + n * ORIG);
    float acc = b[f];
#pragma unroll
    for (int k = 0; k < ORIG; ++k) acc += ar[k] * sW[k * F + f];
    out[n * F + f] = acc;
}

// ---------------- y12 ----------------
__global__ __launch_bounds__(256) void k_y12(const float* __restrict__ a,
                                             const float* __restrict__ W,  // (169,128)
                                             float* __restrict__ y1,
                                             float* __restrict__ y2) {
    __shared__ __align__(16) float sAT[F][16];
    int base = blockIdx.x * 16;
    int t = threadIdx.x;
#pragma unroll
    for (int i = 0; i < 4; ++i) {
        int e = t + i * 256;
        sAT[e & 63][e >> 6] = a[base * F + e];
    }
    __syncthreads();
    int c = t;
    const float* wp = (c < 128) ? (W + c) : (W + 64 * H + (c - 128));
    float acc[16];
#pragma unroll
    for (int r = 0; r < 16; ++r) acc[r] = 0.f;
#pragma unroll
    for (int k = 0; k < F; ++k) {
        float w = wp[k * H];
        const float4* rp = reinterpret_cast<const float4*>(&sAT[k][0]);
        float4 v0 = rp[0], v1 = rp[1], v2 = rp[2], v3 = rp[3];
        acc[0] += v0.x * w;  acc[1] += v0.y * w;  acc[2] += v0.z * w;  acc[3] += v0.w * w;
        acc[4] += v1.x * w;  acc[5] += v1.y * w;  acc[6] += v1.z * w;  acc[7] += v1.w * w;
        acc[8] += v2.x * w;  acc[9] += v2.y * w;  acc[10] += v2.z * w; acc[11] += v2.w * w;
        acc[12] += v3.x * w; acc[13] += v3.y * w; acc[14] += v3.z * w; acc[15] += v3.w * w;
    }
    float* dst = (c < 128) ? (y1 + base * H + c) : (y2 + base * H + (c - 128));
#pragma unroll
    for (int r = 0; r < 16; ++r) dst[r * H] = acc[r];
}

// ---------------- fused conv layer (in-place update of a) ----------------
__global__ __launch_bounds__(256, 4) void k_conv(const float* __restrict__ y1,
                                                 const float* __restrict__ y2,
                                                 const float* __restrict__ nbr,   // (N,12,41)
                                                 const int* __restrict__ idx,     // (N,12)
                                                 const float* __restrict__ W3,    // (41,128)
                                                 const float* __restrict__ bias,  // (128)
                                                 const float* __restrict__ bn1,   // (4,128)
                                                 const float* __restrict__ bn2,   // (4,64)
                                                 float* __restrict__ a) {
    __shared__ __align__(16) float snv[4 * ATOMROW];  // 4 atoms x 12 nbr x 44 floats
    __shared__ float sS1[128], sH1[128], sS2[64], sH2[64];
    int t = threadIdx.x;
    if (t < 128) {
        float g = bn1[t], be = bn1[128 + t], mu = bn1[256 + t], va = bn1[384 + t];
        float s = g * rsqrtf(va + 1e-5f);
        sS1[t] = s;
        sH1[t] = be - mu * s + bias[t] * s;
    } else if (t < 192) {
        int u = t - 128;
        float g = bn2[u], be = bn2[64 + u], mu = bn2[128 + u], va = bn2[192 + u];
        float s = g * rsqrtf(va + 1e-5f);
        sS2[u] = s;
        sH2[u] = be - mu * s;
    }

    // stage 4 contiguous atoms' nbr rows: coalesced vector loads -> padded LDS
    {
        const float* g = nbr + (size_t)blockIdx.x * (4 * MNBR * NBRF);
#pragma unroll
        for (int it = 0; it < 8; ++it) {
            int e = t + it * 256;
            if (e < 4 * MNBR * NBRF) {
                int a_ = e / (MNBR * NBRF);
                int r  = e - a_ * (MNBR * NBRF);
                int m  = r / NBRF;
                int k  = r - m * NBRF;
                snv[a_ * ATOMROW + m * NVPAD + k] = g[e];
            }
        }
    }
    __syncthreads();

    int w = t >> 6;
    int f = t & 63;
    int i = blockIdx.x * 4 + w;

    const int* ip = upt(idx + i * MNBR);
    int js[MNBR];
#pragma unroll
    for (int m = 0; m < MNBR; ++m) js[m] = ip[m];

    // persistent accumulators seeded with y1[i] + gathered y2[j]
    float yf = y1[i * H + f], yc = y1[i * H + 64 + f];
    float zf[MNBR], zc[MNBR];
#pragma unroll
    for (int m = 0; m < MNBR; ++m) {
        zf[m] = yf + y2[js[m] * H + f];
        zc[m] = yc + y2[js[m] * H + 64 + f];
    }

    const float* base = &snv[w * ATOMROW];  // wave-uniform -> ds broadcast reads
    const float* w3f = W3 + f;              // this lane's filter column
    const float* w3c = W3 + 64 + f;         // this lane's core column

    // k-quad-outer, neighbor-inner; weights streamed with 1-deep prefetch
    float4 wa, wb;
    wa.x = w3f[0 * H]; wa.y = w3f[1 * H]; wa.z = w3f[2 * H]; wa.w = w3f[3 * H];
    wb.x = w3c[0 * H]; wb.y = w3c[1 * H]; wb.z = w3c[2 * H]; wb.w = w3c[3 * H];
#pragma unroll
    for (int c = 0; c < 10; ++c) {
        float4 na, nb;
        if (c < 9) {
            int k0 = 4 * (c + 1);
            na.x = w3f[(k0 + 0) * H]; na.y = w3f[(k0 + 1) * H];
            na.z = w3f[(k0 + 2) * H]; na.w = w3f[(k0 + 3) * H];
            nb.x = w3c[(k0 + 0) * H]; nb.y = w3c[(k0 + 1) * H];
            nb.z = w3c[(k0 + 2) * H]; nb.w = w3c[(k0 + 3) * H];
        } else {
            na.x = w3f[40 * H]; na.y = na.z = na.w = 0.f;
            nb.x = w3c[40 * H]; nb.y = nb.z = nb.w = 0.f;
        }
#pragma unroll
        for (int m = 0; m < MNBR; ++m) {
            float4 q = *reinterpret_cast<const float4*>(base + m * NVPAD + 4 * c);
            zf[m] = fmaf(q.x, wa.x, zf[m]);
            zc[m] = fmaf(q.x, wb.x, zc[m]);
            zf[m] = fmaf(q.y, wa.y, zf[m]);
            zc[m] = fmaf(q.y, wb.y, zc[m]);
            zf[m] = fmaf(q.z, wa.z, zf[m]);
            zc[m] = fmaf(q.z, wb.z, zc[m]);
            zf[m] = fmaf(q.w, wa.w, zf[m]);
            zc[m] = fmaf(q.w, wb.w, zc[m]);
        }
        wa = na; wb = nb;
    }
    // tail k = 40 (weights already in wa.x / wb.x)
#pragma unroll
    for (int m = 0; m < MNBR; ++m) {
        float nv40 = base[m * NVPAD + 40];
        zf[m] = fmaf(nv40, wa.x, zf[m]);
        zc[m] = fmaf(nv40, wb.x, zc[m]);
    }

    float s1f = sS1[f], h1f = sH1[f], s1c = sS1[64 + f], h1c = sH1[64 + f];
    float s2 = sS2[f], h2 = sH2[f];
    float sacc = 0.f;
#pragma unroll
    for (int m = 0; m < MNBR; ++m) {
        float vf = zf[m] * s1f + h1f;
        float vc = zc[m] * s1c + h1c;
        sacc += sigmoidf(vf) * softplusf(vc);
    }
    float av = a[i * F + f];
    a[i * F + f] = softplusf(av + sacc * s2 + h2);
}

// ---------------- pool ----------------
__global__ __launch_bounds__(256) void k_pool(const float* __restrict__ a,
                                              const int* __restrict__ seg,
                                              float* __restrict__ pool,
                                              float* __restrict__ cnt) {
    int idx = blockIdx.x * 256 + threadIdx.x;
    int n = idx >> 6, f = idx & 63;
    int c = seg[n];
    atomicAdd(&pool[c * F + f], a[idx]);
    if (f == 0) atomicAdd(&cnt[c], 1.f);
}

// ---------------- dense ----------------
__global__ __launch_bounds__(128) void k_dense(const float* __restrict__ pool,
                                               const float* __restrict__ cnt,
                                               const float* __restrict__ W,
                                               const float* __restrict__ b,
                                               float* __restrict__ crys) {
    int c = blockIdx.x;
    int h = threadIdx.x;
    __shared__ float sp[F];
    if (h < F) sp[h] = pool[c * F + h] / fmaxf(cnt[c], 1.f);
    __syncthreads();
    float acc = b[h];
#pragma unroll
    for (int k = 0; k < F; ++k) acc += sp[k] * W[k * H + h];
    crys[c * H + h] = softplusf(acc);
}

// ---------------- combine ----------------
__global__ __launch_bounds__(128) void k_combine(const float* __restrict__ cA,
                                                 const float* __restrict__ cB,
                                                 const float* __restrict__ ffW,
                                                 const float* __restrict__ ffb,
                                                 const float* __restrict__ outW,
                                                 const float* __restrict__ outb,
                                                 float* __restrict__ out) {
    int c = blockIdx.x;
    int h = threadIdx.x;
    __shared__ float sd[H];
    __shared__ float st[H];
    sd[h] = fabsf(cA[c * H + h] - cB[c * H + h]);
    __syncthreads();
    float acc = ffb[h];
#pragma unroll
    for (int k = 0; k < H; ++k) acc += sd[k] * ffW[k * H + h];
    st[h] = softplusf(acc) * outW[h];
    __syncthreads();
    for (int s = 64; s > 0; s >>= 1) {
        if (h < s) st[h] += st[h + s];
        __syncthreads();
    }
    if (h == 0) out[c] = st[0] + outb[0];
}

extern "C" void kernel_launch(void* const* d_in, const int* in_sizes, int n_in,
                              void* d_out, int out_size, void* d_ws, size_t ws_size,
                              hipStream_t stream) {
    const float* ffW  = (const float*)d_in[24];
    const float* ffb  = (const float*)d_in[25];
    const float* outW = (const float*)d_in[26];
    const float* outb = (const float*)d_in[27];

    float* ws = (float*)d_ws;
    float* aA    = ws;
    float* aB    = aA + NATOM * F;
    float* y1    = aB + NATOM * F;
    float* y2    = y1 + NATOM * H;
    float* poolA = y2 + NATOM * H;
    float* poolB = poolA + NCRYS * F;
    float* cntA  = poolB + NCRYS * F;
    float* cntB  = cntA + NCRYS;
    float* crA   = cntB + NCRYS;
    float* crB   = crA + NCRYS * H;

    hipMemsetAsync(poolA, 0, (size_t)(2 * NCRYS * F + 2 * NCRYS) * sizeof(float), stream);

    for (int br = 0; br < 2; ++br) {
        int o = br * 12;
        const float* atom  = (const float*)d_in[o + 0];
        const float* nbrf  = (const float*)d_in[o + 1];
        const int*   nidx  = (const int*)d_in[o + 2];
        const int*   seg   = (const int*)d_in[o + 3];
        const float* embW  = (const float*)d_in[o + 4];
        const float* embb  = (const float*)d_in[o + 5];
        const float* convW = (const float*)d_in[o + 6];
        const float* convb = (const float*)d_in[o + 7];
        const float* bn1   = (const float*)d_in[o + 8];
        const float* bn2   = (const float*)d_in[o + 9];
        const float* denW  = (const float*)d_in[o + 10];
        const float* denb  = (const float*)d_in[o + 11];

        float* a    = br ? aB : aA;
        float* pool = br ? poolB : poolA;
        float* cnt  = br ? cntB : cntA;
        float* cr   = br ? crB : crA;

        k_embed<<<NATOM / 4, 256, 0, stream>>>(atom, embW, embb, a);
        for (int l = 0; l < NCONV; ++l) {
            const float* Wl = convW + (size_t)l * (2 * F + NBRF) * H;
            k_y12<<<NATOM / 16, 256, 0, stream>>>(a, Wl, y1, y2);
            k_conv<<<NATOM / 4, 256, 0, stream>>>(y1, y2, nbrf, nidx,
                                                  Wl + 128 * H,
                                                  convb + l * H,
                                                  bn1 + l * 4 * H,
                                                  bn2 + l * 4 * F,
                                                  a);
        }
        k_pool<<<NATOM * F / 256, 256, 0, stream>>>(a, seg, pool, cnt);
        k_dense<<<NCRYS, 128, 0, stream>>>(pool, cnt, denW, denb, cr);
    }

    k_combine<<<NCRYS, 128, 0, stream>>>(crA, crB, ffW, ffb, outW, outb, (float*)d_out);
}

// Round 4
// 468.603 us; speedup vs baseline: 2.6531x; 1.2432x over previous
//
#include <hip/hip_runtime.h>

// Paired CGCNN (separated) — R3.
// R3 change: k_conv replaced by k_convfused — MFMA (bf16 16x16x32) computes the
// nbr_fea@W3 part of z for 48 rows x 128 cols per block (4 atoms), epilogue in
// the same kernel adds y1[i]+y2[j], BN1, sigmoid*softplus, reduces over the 12
// neighbors, BN2 + residual. No znbr materialization; LDS z-tile aliases the
// dead A/W staging regions. y12/embed/pool/dense/combine unchanged (fp32).

constexpr int NATOM = 20000;
constexpr int MNBR  = 12;
constexpr int ORIG  = 92;
constexpr int NBRF  = 41;
constexpr int F     = 64;
constexpr int H     = 128;
constexpr int NCONV = 3;
constexpr int NCRYS = 400;

#define DEVFN __device__ __forceinline__

typedef __attribute__((ext_vector_type(8))) short short8;   // 8 bf16 (4 VGPR)
typedef __attribute__((ext_vector_type(4))) float f32x4;    // MFMA acc

DEVFN float softplusf(float x) {
    return fmaxf(x, 0.f) + __logf(1.f + __expf(-fabsf(x)));
}
DEVFN float sigmoidf(float x) {
    return __builtin_amdgcn_rcpf(1.f + __expf(-x));
}
DEVFN unsigned short f2bf(float x) {  // RNE fp32->bf16
    union { float f; unsigned u; } v{x};
    unsigned r = v.u + 0x7FFF + ((v.u >> 16) & 1);
    return (unsigned short)(r >> 16);
}

template <typename T>
DEVFN const T* upt(const T* p) {
    unsigned long long v = (unsigned long long)p;
    unsigned lo = __builtin_amdgcn_readfirstlane((unsigned)v);
    unsigned hi = __builtin_amdgcn_readfirstlane((unsigned)(v >> 32));
    return (const T*)((((unsigned long long)hi) << 32) | lo);
}

// ---------------- embed ----------------
__global__ __launch_bounds__(256) void k_embed(const float* __restrict__ atom,
                                               const float* __restrict__ W,
                                               const float* __restrict__ b,
                                               float* __restrict__ out) {
    __shared__ float sW[ORIG * F];
    for (int i = threadIdx.x; i < ORIG * F; i += 256) sW[i] = W[i];
    __syncthreads();
    int n = blockIdx.x * 4 + (threadIdx.x >> 6);
    int f = threadIdx.x & 63;
    const float* ar = upt(atom + n * ORIG);
    float acc = b[f];
#pragma unroll
    for (int k = 0; k < ORIG; ++k) acc += ar[k] * sW[k * F + f];
    out[n * F + f] = acc;
}

// ---------------- y12 ----------------
__global__ __launch_bounds__(256) void k_y12(const float* __restrict__ a,
                                             const float* __restrict__ W,  // (169,128)
                                             float* __restrict__ y1,
                                             float* __restrict__ y2) {
    __shared__ __align__(16) float sAT[F][16];
    int base = blockIdx.x * 16;
    int t = threadIdx.x;
#pragma unroll
    for (int i = 0; i < 4; ++i) {
        int e = t + i * 256;
        sAT[e & 63][e >> 6] = a[base * F + e];
    }
    __syncthreads();
    int c = t;
    const float* wp = (c < 128) ? (W + c) : (W + 64 * H + (c - 128));
    float acc[16];
#pragma unroll
    for (int r = 0; r < 16; ++r) acc[r] = 0.f;
#pragma unroll
    for (int k = 0; k < F; ++k) {
        float w = wp[k * H];
        const float4* rp = reinterpret_cast<const float4*>(&sAT[k][0]);
        float4 v0 = rp[0], v1 = rp[1], v2 = rp[2], v3 = rp[3];
        acc[0] += v0.x * w;  acc[1] += v0.y * w;  acc[2] += v0.z * w;  acc[3] += v0.w * w;
        acc[4] += v1.x * w;  acc[5] += v1.y * w;  acc[6] += v1.z * w;  acc[7] += v1.w * w;
        acc[8] += v2.x * w;  acc[9] += v2.y * w;  acc[10] += v2.z * w; acc[11] += v2.w * w;
        acc[12] += v3.x * w; acc[13] += v3.y * w; acc[14] += v3.z * w; acc[15] += v3.w * w;
    }
    float* dst = (c < 128) ? (y1 + base * H + c) : (y2 + base * H + (c - 128));
#pragma unroll
    for (int r = 0; r < 16; ++r) dst[r * H] = acc[r];
}

// ---------------- fused conv layer: MFMA z-tile + epilogue reduce ----------------
// Block = 4 atoms = 48 nbr-rows; cols 0..127. 4 waves, wave w does cols w*32..+31.
// LDS layout (27072 B):
//   [0,     6912)  sA  : 48 rows x 72 bf16 (K 0..63, zeros past 41; stride 144B)
//   [6912, 25344)  sW  : 128 cols x 72 bf16 (W3^T, zeros past 41)
//   [0,    25344)  sZ  : 48 x 132 f32 (aliases sA+sW after MFMA phase)
//   [25344,26880)  BN  : sS1[128] sH1[128] sS2[64] sH2[64]
//   [26880,27072)  sJ  : 48 neighbor indices
__global__ __launch_bounds__(256, 4) void k_convfused(
        const float* __restrict__ y1,
        const float* __restrict__ y2,
        const float* __restrict__ nbr,   // (N,12,41) fp32
        const int* __restrict__ idx,     // (N,12)
        const float* __restrict__ W3,    // (41,128) fp32
        const float* __restrict__ bias,  // (128)
        const float* __restrict__ bn1,   // (4,128)
        const float* __restrict__ bn2,   // (4,64)
        float* __restrict__ a) {
    __shared__ __align__(16) unsigned char pool[27072];
    unsigned short* sA = (unsigned short*)pool;
    unsigned short* sW = (unsigned short*)(pool + 6912);
    float* sZ  = (float*)pool;
    float* sS1 = (float*)(pool + 25344);
    float* sH1 = sS1 + 128;
    float* sS2 = sH1 + 128;
    float* sH2 = sS2 + 64;
    int*   sJ  = (int*)(pool + 26880);

    int t = threadIdx.x;
    int atom0 = blockIdx.x * 4;
    int R0 = atom0 * MNBR;  // global nbr-row base (48 rows)

    // --- stage A: nbr rows fp32 -> bf16, K padded to 64 with zeros ---
    {
        const float* g = nbr + (size_t)R0 * NBRF;
#pragma unroll
        for (int it = 0; it < 6; ++it) {        // 48 rows x 32 k-pairs = 1536
            int e = t + it * 256;
            int r = e >> 5, kp = e & 31, k = kp * 2;
            float v0 = (k < NBRF) ? g[r * NBRF + k] : 0.f;
            float v1 = (k + 1 < NBRF) ? g[r * NBRF + k + 1] : 0.f;
            unsigned pk = (unsigned)f2bf(v0) | ((unsigned)f2bf(v1) << 16);
            ((unsigned*)sA)[r * 36 + kp] = pk;  // row stride 72 ushort = 36 uint
        }
    }
    // --- stage W3^T: sW[c][k] = W3[k*128+c], zeros k>=41 ---
    {
#pragma unroll
        for (int it = 0; it < 16; ++it) {       // 128 cols x 32 k-pairs = 4096
            int e = t + it * 256;
            int c = e & 127, kp = e >> 7, k = kp * 2;
            float v0 = (k < NBRF) ? W3[k * H + c] : 0.f;
            float v1 = (k + 1 < NBRF) ? W3[(k + 1) * H + c] : 0.f;
            unsigned pk = (unsigned)f2bf(v0) | ((unsigned)f2bf(v1) << 16);
            ((unsigned*)sW)[c * 36 + kp] = pk;
        }
    }
    // --- BN fold + neighbor indices ---
    if (t < 128) {
        float g = bn1[t], be = bn1[128 + t], mu = bn1[256 + t], va = bn1[384 + t];
        float s = g * rsqrtf(va + 1e-5f);
        sS1[t] = s;
        sH1[t] = be - mu * s + bias[t] * s;
    } else if (t < 192) {
        int u = t - 128;
        float g = bn2[u], be = bn2[64 + u], mu = bn2[128 + u], va = bn2[192 + u];
        float s = g * rsqrtf(va + 1e-5f);
        sS2[u] = s;
        sH2[u] = be - mu * s;
    }
    if (t < 48) sJ[t] = idx[R0 + t];
    __syncthreads();

    // --- MFMA phase: wave w -> cols CB..CB+31; 3 row-frags x 2 col-frags ---
    int w = t >> 6, lane = t & 63;
    int lr = lane & 15, lq = lane >> 4;
    int CB = w * 32;
    f32x4 acc[2][3];
#pragma unroll
    for (int n = 0; n < 2; ++n)
#pragma unroll
        for (int r = 0; r < 3; ++r) acc[n][r] = f32x4{0.f, 0.f, 0.f, 0.f};

#pragma unroll
    for (int kstep = 0; kstep < 2; ++kstep) {
        int ks = kstep * 32 + lq * 8;
        short8 af[3], bf[2];
#pragma unroll
        for (int r = 0; r < 3; ++r) {
            int row = r * 16 + lr;
            af[r] = *(const short8*)(pool + (size_t)row * 144 + ks * 2);
        }
#pragma unroll
        for (int n = 0; n < 2; ++n) {
            int col = CB + n * 16 + lr;
            bf[n] = *(const short8*)(pool + 6912 + (size_t)col * 144 + ks * 2);
        }
#pragma unroll
        for (int n = 0; n < 2; ++n)
#pragma unroll
            for (int r = 0; r < 3; ++r)
                acc[n][r] = __builtin_amdgcn_mfma_f32_16x16x32_bf16(af[r], bf[n], acc[n][r], 0, 0, 0);
    }
    __syncthreads();  // all waves done reading sA/sW -> safe to overwrite with sZ

    // --- spill z-tile to LDS: D layout col=lane&15, row=(lane>>4)*4+reg ---
#pragma unroll
    for (int n = 0; n < 2; ++n)
#pragma unroll
        for (int r = 0; r < 3; ++r)
#pragma unroll
            for (int q = 0; q < 4; ++q) {
                int row = r * 16 + lq * 4 + q;
                int col = CB + n * 16 + lr;
                sZ[row * 132 + col] = acc[n][r][q];
            }
    __syncthreads();

    // --- epilogue: thread = (atom, feature); reduce 12 neighbors ---
    int al = t >> 6, f = t & 63;
    int i = atom0 + al;
    float y1f = y1[i * H + f], y1c = y1[i * H + 64 + f];
    float s1f = sS1[f], h1f = sH1[f], s1c = sS1[64 + f], h1c = sH1[64 + f];

    int js[MNBR];
#pragma unroll
    for (int m = 0; m < MNBR; ++m) js[m] = sJ[al * MNBR + m];
    float gf[MNBR], gc[MNBR];
#pragma unroll
    for (int m = 0; m < MNBR; ++m) {
        gf[m] = y2[js[m] * H + f];
        gc[m] = y2[js[m] * H + 64 + f];
    }

    float sacc = 0.f;
#pragma unroll
    for (int m = 0; m < MNBR; ++m) {
        int row = al * MNBR + m;
        float zf = sZ[row * 132 + f] + y1f + gf[m];
        float zc = sZ[row * 132 + 64 + f] + y1c + gc[m];
        zf = zf * s1f + h1f;
        zc = zc * s1c + h1c;
        sacc += sigmoidf(zf) * softplusf(zc);
    }
    float av = a[i * F + f];
    a[i * F + f] = softplusf(av + sacc * sS2[f] + sH2[f]);
}

// ---------------- pool ----------------
__global__ __launch_bounds__(256) void k_pool(const float* __restrict__ a,
                                              const int* __restrict__ seg,
                                              float* __restrict__ pool,
                                              float* __restrict__ cnt) {
    int idx = blockIdx.x * 256 + threadIdx.x;
    int n = idx >> 6, f = idx & 63;
    int c = seg[n];
    atomicAdd(&pool[c * F + f], a[idx]);
    if (f == 0) atomicAdd(&cnt[c], 1.f);
}

// ---------------- dense ----------------
__global__ __launch_bounds__(128) void k_dense(const float* __restrict__ pool,
                                               const float* __restrict__ cnt,
                                               const float* __restrict__ W,
                                               const float* __restrict__ b,
                                               float* __restrict__ crys) {
    int c = blockIdx.x;
    int h = threadIdx.x;
    __shared__ float sp[F];
    if (h < F) sp[h] = pool[c * F + h] / fmaxf(cnt[c], 1.f);
    __syncthreads();
    float acc = b[h];
#pragma unroll
    for (int k = 0; k < F; ++k) acc += sp[k] * W[k * H + h];
    crys[c * H + h] = softplusf(acc);
}

// ---------------- combine ----------------
__global__ __launch_bounds__(128) void k_combine(const float* __restrict__ cA,
                                                 const float* __restrict__ cB,
                                                 const float* __restrict__ ffW,
                                                 const float* __restrict__ ffb,
                                                 const float* __restrict__ outW,
                                                 const float* __restrict__ outb,
                                                 float* __restrict__ out) {
    int c = blockIdx.x;
    int h = threadIdx.x;
    __shared__ float sd[H];
    __shared__ float st[H];
    sd[h] = fabsf(cA[c * H + h] - cB[c * H + h]);
    __syncthreads();
    float acc = ffb[h];
#pragma unroll
    for (int k = 0; k < H; ++k) acc += sd[k] * ffW[k * H + h];
    st[h] = softplusf(acc) * outW[h];
    __syncthreads();
    for (int s = 64; s > 0; s >>= 1) {
        if (h < s) st[h] += st[h + s];
        __syncthreads();
    }
    if (h == 0) out[c] = st[0] + outb[0];
}

extern "C" void kernel_launch(void* const* d_in, const int* in_sizes, int n_in,
                              void* d_out, int out_size, void* d_ws, size_t ws_size,
                              hipStream_t stream) {
    const float* ffW  = (const float*)d_in[24];
    const float* ffb  = (const float*)d_in[25];
    const float* outW = (const float*)d_in[26];
    const float* outb = (const float*)d_in[27];

    float* ws = (float*)d_ws;
    float* aA    = ws;
    float* aB    = aA + NATOM * F;
    float* y1    = aB + NATOM * F;
    float* y2    = y1 + NATOM * H;
    float* poolA = y2 + NATOM * H;
    float* poolB = poolA + NCRYS * F;
    float* cntA  = poolB + NCRYS * F;
    float* cntB  = cntA + NCRYS;
    float* crA   = cntB + NCRYS;
    float* crB   = crA + NCRYS * H;

    hipMemsetAsync(poolA, 0, (size_t)(2 * NCRYS * F + 2 * NCRYS) * sizeof(float), stream);

    for (int br = 0; br < 2; ++br) {
        int o = br * 12;
        const float* atom  = (const float*)d_in[o + 0];
        const float* nbrf  = (const float*)d_in[o + 1];
        const int*   nidx  = (const int*)d_in[o + 2];
        const int*   seg   = (const int*)d_in[o + 3];
        const float* embW  = (const float*)d_in[o + 4];
        const float* embb  = (const float*)d_in[o + 5];
        const float* convW = (const float*)d_in[o + 6];
        const float* convb = (const float*)d_in[o + 7];
        const float* bn1   = (const float*)d_in[o + 8];
        const float* bn2   = (const float*)d_in[o + 9];
        const float* denW  = (const float*)d_in[o + 10];
        const float* denb  = (const float*)d_in[o + 11];

        float* a    = br ? aB : aA;
        float* pool = br ? poolB : poolA;
        float* cnt  = br ? cntB : cntA;
        float* cr   = br ? crB : crA;

        k_embed<<<NATOM / 4, 256, 0, stream>>>(atom, embW, embb, a);
        for (int l = 0; l < NCONV; ++l) {
            const float* Wl = convW + (size_t)l * (2 * F + NBRF) * H;
            k_y12<<<NATOM / 16, 256, 0, stream>>>(a, Wl, y1, y2);
            k_convfused<<<NATOM / 4, 256, 0, stream>>>(y1, y2, nbrf, nidx,
                                                       Wl + 128 * H,
                                                       convb + l * H,
                                                       bn1 + l * 4 * H,
                                                       bn2 + l * 4 * F,
                                                       a);
        }
        k_pool<<<NATOM * F / 256, 256, 0, stream>>>(a, seg, pool, cnt);
        k_dense<<<NCRYS, 128, 0, stream>>>(pool, cnt, denW, denb, cr);
    }

    k_combine<<<NCRYS, 128, 0, stream>>>(crA, crB, ffW, ffb, outW, outb, (float*)d_out);
}